// Round 5
// baseline (162.441 us; speedup 1.0000x reference)
//
#include <hip/hip_runtime.h>

// Post_Prob_GS: B=8, N=256 points, grid 128x128 (HW=16384), stride 4.
// out[b, n, hw] = softmax over n of likelihood; n==256 is the background term.
//
// Round 5 structure (split reduce / store to fix the write pattern):
//  - prep_kernel: packs per-point coeffs (expanded quadratic, log2e-scaled).
//  - reduce_kernel: per (b,hw) computes m2 = mf + log2(sum) into ws (streamed
//    coeff evals, no register cache -> low VGPR, full occupancy) and writes
//    the background row.
//  - store_kernel: one (b,n) row per block, 1024 consecutive hw per block,
//    one float4 store per thread -> 1KB contiguous per wave-store, streaming
//    writes like the fill kernel (round-3 counters showed the old n-walking
//    256B-stride pattern ran at 1.1 TB/s; this should run at ~6).

#define HWC 16384
#define NPTS 256
#define NBATCH 8

#define K_LOG2E 1.4426950408889634f
// log2e*(-0.5*100^2) + log2(0.15)
#define BK_CONST (-7216.2121700389835f)

__global__ __launch_bounds__(256) void prep_kernel(
    const float* __restrict__ scale,     // (B,N,2)
    const float* __restrict__ rotation,  // (B,N,1)
    const float* __restrict__ points,    // (B,N,2)
    float4* __restrict__ P)              // (B*N) x 2 float4
{
    const int i = blockIdx.x * 256 + threadIdx.x;   // 0..2047 = b*256+n
    if (i >= NBATCH * NPTS) return;

    float sx = fminf(fmaxf(32.0f * scale[i * 2 + 0], 2.0f), 100.0f);
    float sy = fminf(fmaxf(32.0f * scale[i * 2 + 1], 2.0f), 100.0f);
    float sx2 = sx * sx, sy2 = sy * sy;

    float th = rotation[i];
    float s, c;
    sincosf(th, &s, &c);
    float cov_a = c * c * sx2 + s * s * sy2;
    float cov_b = c * s * (sx2 - sy2);
    float cov_d = s * s * sx2 + c * c * sy2;
    float det  = sx2 * sy2;
    float rdet = 1.0f / det;

    // z = -0.5*(inv_a dx^2 + 2 inv_b dx dy + inv_d dy^2); all scaled by log2e
    float KA = -0.5f * K_LOG2E * (cov_d * rdet);
    float KB =         K_LOG2E * (cov_b * rdet);
    float KD = -0.5f * K_LOG2E * (cov_a * rdet);

    float px = points[i * 2 + 0];
    float py = points[i * 2 + 1];

    // expand: zK = KA*gx^2 + KB*gx*gy + KD*gy^2 + cx*gx + cy*gy + cz
    float cx = -(2.0f * KA * px + KB * py);
    float cy = -(KB * px + 2.0f * KD * py);
    float cz = KA * px * px + KB * px * py + KD * py * py;

    float l2det = log2f(det);
    float HLK = -0.5f * l2det;

    P[i * 2 + 0] = make_float4(KA, KB, KD, cx);
    P[i * 2 + 1] = make_float4(cy, cz + HLK, HLK, l2det);
}

#define LIKE(q0, q1) fmaf((q0).x, gxx, fmaf((q0).y, gxy, fmaf((q0).z, gyy, \
                     fmaf((q0).w, gx,  fmaf((q1).x, gy, (q1).y)))))

// m2[b,hw] = softmax log-normalizer (log2 domain); also writes bk output row.
__global__ __launch_bounds__(512) void reduce_kernel(
    const float4* __restrict__ P,    // packed coeffs in ws
    float* __restrict__ m2arr,       // (B, HW) in ws
    float* __restrict__ out)         // (B, 257, HW) -- bk row only
{
    __shared__ float sM[512];
    __shared__ float sBZ[512];
    __shared__ float sBLD[512];
    __shared__ float sS[512];

    const int b      = blockIdx.x >> 8;          // 256 blocks per batch
    const int hwbase = (blockIdx.x & 255) << 6;  // 64 hw per block
    const int tid    = threadIdx.x;
    const int h      = tid & 63;                 // hw within block (lane)
    const int hw     = hwbase + h;
    // n-group 0..7; readfirstlane => SGPR => scalar coefficient loads
    const int g      = __builtin_amdgcn_readfirstlane(tid >> 6);

    const float gx = (float)((hw & 127) * 4 + 2);
    const float gy = (float)((hw >> 7) * 4 + 2);
    const float gxx = gx * gx, gxy = gx * gy, gyy = gy * gy;

    const float4* __restrict__ Pb = P + (b * NPTS + g * 32) * 2;

    // ---- pass A: per-thread max + first-argmax over 32 points (streamed) ----
    float m = -INFINITY, bz = -INFINITY, bld = 0.0f;
    #pragma unroll 8
    for (int i = 0; i < 32; ++i) {
        float4 q0 = Pb[i * 2 + 0];
        float4 q1 = Pb[i * 2 + 1];
        float like = LIKE(q0, q1);
        m = fmaxf(m, like);
        float z = like - q1.z;
        bool gt = z > bz;               // strict > : first occurrence wins
        bz  = gt ? z    : bz;
        bld = gt ? q1.w : bld;
    }
    sM[tid] = m; sBZ[tid] = bz; sBLD[tid] = bld;
    __syncthreads();

    // merge groups in ascending g (== ascending n: first-max wins)
    float mf = sM[h], bzf = sBZ[h], bldf = sBLD[h];
    #pragma unroll
    for (int q = 1; q < 8; ++q) {
        mf = fmaxf(mf, sM[h + q * 64]);
        float zq = sBZ[h + q * 64];
        bool gt = zq > bzf;
        bzf  = gt ? zq : bzf;
        bldf = gt ? sBLD[h + q * 64] : bldf;
    }
    const float bk = BK_CONST - bzf - bldf;
    mf = fmaxf(mf, bk);

    // ---- pass B: sum of exp2 (recompute likes; cheap vs occupancy cost) ----
    float s = 0.0f;
    #pragma unroll 8
    for (int i = 0; i < 32; ++i) {
        float4 q0 = Pb[i * 2 + 0];
        float4 q1 = Pb[i * 2 + 1];
        s += exp2f(LIKE(q0, q1) - mf);
    }
    sS[tid] = s;
    __syncthreads();

    float sum = exp2f(bk - mf);
    #pragma unroll
    for (int q = 0; q < 8; ++q) sum += sS[h + q * 64];
    const float m2 = mf + log2f(sum);   // folds 1/sum into the exponent

    if (tid < 64) {
        m2arr[b * HWC + hw] = m2;
        out[((size_t)b * 257 + 256) * HWC + hw] = exp2f(bk - m2);
    }
}

// One (b,n) row per block; 1024 consecutive hw per block; float4 stores.
__global__ __launch_bounds__(256) void store_kernel(
    const float4* __restrict__ P,    // packed coeffs in ws
    const float* __restrict__ m2arr, // (B, HW) in ws
    float* __restrict__ out)         // (B, 257, HW)
{
    const int bid   = blockIdx.x;
    const int bn    = bid >> 4;          // b*256+n  (wave-uniform)
    const int chunk = bid & 15;          // 16 chunks of 1024 hw
    const int b     = bn >> 8;
    const int tid   = threadIdx.x;
    const int hw    = chunk * 1024 + tid * 4;

    // coeffs: uniform address -> s_load through constant cache
    float4 q0 = P[bn * 2 + 0];
    float4 q1 = P[bn * 2 + 1];

    const int x0 = hw & 127;             // 4-aligned, never crosses a row
    const float gy = (float)((hw >> 7) * 4 + 2);
    const float cyt = fmaf(q1.x, gy, q1.y);       // cy*gy + (cz+HLK)
    const float kdy = q0.z * gy * gy;             // KD*gy^2
    const float base = cyt + kdy;

    float4 mm = *reinterpret_cast<const float4*>(m2arr + b * HWC + hw);

    float e[4];
    #pragma unroll
    for (int j = 0; j < 4; ++j) {
        float gx = (float)((x0 + j) * 4 + 2);
        // like = KA*gx^2 + (KB*gy + cx)*gx + base
        float like = fmaf(fmaf(q0.x, gx, fmaf(q0.y, gy, q0.w)), gx, base);
        float mj = (j == 0) ? mm.x : (j == 1) ? mm.y : (j == 2) ? mm.z : mm.w;
        e[j] = exp2f(like - mj);
    }

    // out row index: b*257 + n == bn + b
    float* dst = out + (size_t)(bn + b) * HWC + hw;
    *reinterpret_cast<float4*>(dst) = make_float4(e[0], e[1], e[2], e[3]);
}

extern "C" void kernel_launch(void* const* d_in, const int* in_sizes, int n_in,
                              void* d_out, int out_size, void* d_ws, size_t ws_size,
                              hipStream_t stream) {
    const float* scale    = (const float*)d_in[0];
    const float* rotation = (const float*)d_in[1];
    const float* points   = (const float*)d_in[2];
    float* out = (float*)d_out;
    float4* P  = (float4*)d_ws;                               // 64 KB
    float* m2  = (float*)((char*)d_ws + 65536);               // 512 KB
    (void)in_sizes; (void)n_in; (void)out_size; (void)ws_size;

    prep_kernel<<<dim3(NBATCH), dim3(256), 0, stream>>>(scale, rotation, points, P);
    reduce_kernel<<<dim3(NBATCH * (HWC / 64)), dim3(512), 0, stream>>>(P, m2, out);
    store_kernel<<<dim3(NBATCH * NPTS * 16), dim3(256), 0, stream>>>(P, m2, out);
}